// Round 12
// baseline (241.969 us; speedup 1.0000x reference)
//
#include <hip/hip_runtime.h>

// Problem constants (from reference)
constexpr int N = 2;
constexpr int C = 20;
constexpr int H = 64;
constexpr int W = 2048;          // power of two -> wrap via & (W-1)
constexpr int HW = H * W;

constexpr int BLK   = 256;       // 4 waves; wave v owns rows {h0+2v, h0+2v+1} x 64 cols
constexpr int BAND  = 8;         // output rows per block
constexpr int CT    = 64;        // output cols per block
constexpr int SROWS = 6;         // staged rows per wave slab (2 out rows + 4 halo)
constexpr int SCOLS = 72;        // staged cols (wc0-4 .. wc0+67)
constexpr int RITEMS = 108;      // real float4 items per slab (6*18)
constexpr int SLABF = 512;       // slab stride in floats (432 used + pad) = 2048 B
constexpr int SLABB = 2048;
// LDS = 4 waves x 3 slabs x 2048 B = 24576 B
// grid = N*(H/BAND)*(W/CT) = 2*8*32 = 512 blocks -> 2 blocks/CU, 8 waves/CU

#define GLDS16(g, l)                                                        \
    __builtin_amdgcn_global_load_lds(                                       \
        (const __attribute__((address_space(1))) void*)(g),                 \
        (__attribute__((address_space(3))) void*)(l), 16, 0, 0)

__global__ __launch_bounds__(BLK, 4)
void lcl_xyz_kernel(const float* __restrict__ xyz,
                    const float* __restrict__ softmax,
                    const int* __restrict__ mask,
                    float* __restrict__ out) {
    __shared__ __align__(16) float lds[4 * 3 * SLABF];   // 24576 B

    const int t  = threadIdx.x;
    const int l  = t & 63;                 // lane
    const int wv = t >> 6;                 // wave 0..3

    // XCD-contiguous swizzle: XCD (bid%8) owns 64 consecutive work ids
    // = 2 full (n,band) slabs -> adjacent bands pair on one L2.
    const int bid  = blockIdx.x;
    const int work = (bid & 7) * 64 + (bid >> 3);   // bijective over [0,512)
    const int ct   = work & 31;                     // col tile
    const int nb   = work >> 5;                     // n*8 + band
    const int n    = nb >> 3;
    const int band = nb & 7;
    const int h0   = band * BAND;
    const int wc0  = ct * CT;

    const int s    = l >> 5;               // sub-row 0/1
    const int orow = h0 + 2 * wv + s;      // absolute output row
    const int oc   = wc0 + 2 * (l & 31);   // first output col (even)

    const float* xb  = xyz + (size_t)(n * 3 + 0) * HW;
    const float* yb  = xyz + (size_t)(n * 3 + 1) * HW;
    const float* zb  = xyz + (size_t)(n * 3 + 2) * HW;
    const int*   mb  = mask + (size_t)n * HW;
    const float* smb = softmax + (size_t)n * C * HW;

    // ---- Weight phase: direct global float2 loads (one-time, no LDS, no sync) ----
    int  rowoff[5];
    bool hv[5];
    #pragma unroll
    for (int j = 0; j < 5; ++j) {
        int hh = orow - 2 + j;
        hv[j] = (unsigned)hh < (unsigned)H;
        rowoff[j] = min(max(hh, 0), H - 1) * W;
    }
    const int cm = (oc - 2) & (W - 1);
    const int c0 = oc;
    const int cp = (oc + 2) & (W - 1);

    const float2 cx2 = *(const float2*)(xb + orow * W + c0);
    const float2 cy2 = *(const float2*)(yb + orow * W + c0);
    const float2 cz2 = *(const float2*)(zb + orow * W + c0);

    float wa[5][5], wb_[5][5];
    #pragma unroll
    for (int r = 0; r < 5; ++r) {
        float2 xm = *(const float2*)(xb + rowoff[r] + cm);
        float2 x0 = *(const float2*)(xb + rowoff[r] + c0);
        float2 xp = *(const float2*)(xb + rowoff[r] + cp);
        float2 ym = *(const float2*)(yb + rowoff[r] + cm);
        float2 y0 = *(const float2*)(yb + rowoff[r] + c0);
        float2 yp = *(const float2*)(yb + rowoff[r] + cp);
        float2 zm = *(const float2*)(zb + rowoff[r] + cm);
        float2 z0 = *(const float2*)(zb + rowoff[r] + c0);
        float2 zp = *(const float2*)(zb + rowoff[r] + cp);
        int2   km = *(const int2*)(mb + rowoff[r] + cm);
        int2   k0 = *(const int2*)(mb + rowoff[r] + c0);
        int2   kp = *(const int2*)(mb + rowoff[r] + cp);

        const float xv[6] = {xm.x, xm.y, x0.x, x0.y, xp.x, xp.y};
        const float yv[6] = {ym.x, ym.y, y0.x, y0.y, yp.x, yp.y};
        const float zv[6] = {zm.x, zm.y, z0.x, z0.y, zp.x, zp.y};
        const int   mv[6] = {km.x, km.y, k0.x, k0.y, kp.x, kp.y};

        #pragma unroll
        for (int j = 0; j < 5; ++j) {
            float dx = xv[j] - cx2.x, dy = yv[j] - cy2.x, dz = zv[j] - cz2.x;
            float d2 = dx * dx + dy * dy + dz * dz;
            wa[r][j] = (hv[r] && mv[j]) ? d2 : 1e30f;       // masked -> exp -> 0
            float ex = xv[j + 1] - cx2.y, ey = yv[j + 1] - cy2.y, ez = zv[j + 1] - cz2.y;
            float e2 = ex * ex + ey * ey + ez * ez;
            wb_[r][j] = (hv[r] && mv[j + 1]) ? e2 : 1e30f;
        }
    }
    #pragma unroll
    for (int r = 0; r < 5; ++r)
        #pragma unroll
        for (int j = 0; j < 5; ++j) {
            wa[r][j]  = __expf(-0.5f * wa[r][j]);
            wb_[r][j] = __expf(-0.5f * wb_[r][j]);
        }
    // All weight loads consumed above -> retired; vmcnt stream now holds only slabs.

    // ---- Per-wave staging tuples: 2 global_load_lds per class ----
    // Slab covers rows h0+2wv-2 .. h0+2wv+3 (clamped), cols wc0-4 .. wc0+67.
    int so0, so1;
    {
        int r0 = l / 18, k0 = l - 18 * r0;
        so0 = min(max(h0 + 2 * wv - 2 + r0, 0), H - 1) * W
            + ((wc0 - 4 + 4 * k0) & (W - 1));
        int i1 = (64 + l < RITEMS) ? 64 + l : 0;
        int r1 = i1 / 18, k1 = i1 - 18 * r1;
        so1 = min(max(h0 + 2 * wv - 2 + r1, 0), H - 1) * W
            + ((wc0 - 4 + 4 * k1) & (W - 1));
    }
    char*        ldst = (char*)lds + wv * (3 * SLABB) + l * 16;
    const float* wlds = lds + wv * (3 * SLABF);
    const int    lcol = 2 * (l & 31) + 2;   // rel col of leftmost tap

    // ---- Prime pipeline: classes 0..2 into slabs 0..2 (6 loads in flight) ----
    #pragma unroll
    for (int pc = 0; pc < 3; ++pc) {
        const float* sc = smb + (size_t)pc * HW;
        GLDS16(sc + so0, ldst + pc * SLABB);
        if (l < RITEMS - 64) GLDS16(sc + so1, ldst + pc * SLABB + 1024);
    }

    float2 acc[C];

    // Per-wave step: counted vmcnt (wave-private slab -> no barrier anywhere).
#define STEP(K, KLIT)                                                        \
    do {                                                                     \
        asm volatile("s_waitcnt vmcnt(" #KLIT ")" ::: "memory");             \
        const float* rw = wlds + ((K) % 3) * SLABF + lcol;                   \
        float a0 = 0.f, a1 = 0.f;                                            \
        _Pragma("unroll")                                                    \
        for (int r = 0; r < 5; ++r) {                                        \
            const float* q = rw + (s + r) * SCOLS;                           \
            float2 u0 = *(const float2*)(q);                                 \
            float2 u1 = *(const float2*)(q + 2);                             \
            float2 u2 = *(const float2*)(q + 4);                             \
            a0 = fmaf(wa[r][0], u0.x, a0);  a0 = fmaf(wa[r][1], u0.y, a0);   \
            a0 = fmaf(wa[r][2], u1.x, a0);  a0 = fmaf(wa[r][3], u1.y, a0);   \
            a0 = fmaf(wa[r][4], u2.x, a0);                                   \
            a1 = fmaf(wb_[r][0], u0.y, a1); a1 = fmaf(wb_[r][1], u1.x, a1);  \
            a1 = fmaf(wb_[r][2], u1.y, a1); a1 = fmaf(wb_[r][3], u2.x, a1);  \
            a1 = fmaf(wb_[r][4], u2.y, a1);                                  \
        }                                                                    \
        acc[K].x = a0; acc[K].y = a1;                                        \
        __builtin_amdgcn_sched_barrier(0);  /* pin refill after slab reads */\
        if ((K) + 3 < C) {                                                   \
            const float* scn = smb + (size_t)((K) + 3) * HW;                 \
            GLDS16(scn + so0, ldst + ((K) % 3) * SLABB);                     \
            if (l < RITEMS - 64)                                             \
                GLDS16(scn + so1, ldst + ((K) % 3) * SLABB + 1024);          \
        }                                                                    \
    } while (0)

    STEP( 0, 4);  STEP( 1, 4);  STEP( 2, 4);  STEP( 3, 4);  STEP( 4, 4);
    STEP( 5, 4);  STEP( 6, 4);  STEP( 7, 4);  STEP( 8, 4);  STEP( 9, 4);
    STEP(10, 4);  STEP(11, 4);  STEP(12, 4);  STEP(13, 4);  STEP(14, 4);
    STEP(15, 4);  STEP(16, 4);  STEP(17, 4);  STEP(18, 2);  STEP(19, 0);
#undef STEP

    // ---- Epilogue: coalesced float2 stores (20 classes) ----
    float* ob = out + (size_t)n * C * HW + (size_t)orow * W + oc;
    #pragma unroll
    for (int c = 0; c < C; ++c)
        *(float2*)(ob + (size_t)c * HW) = acc[c];
}

extern "C" void kernel_launch(void* const* d_in, const int* in_sizes, int n_in,
                              void* d_out, int out_size, void* d_ws, size_t ws_size,
                              hipStream_t stream) {
    const float* xyz     = (const float*)d_in[0];
    const float* softmax = (const float*)d_in[1];
    const int*   mask    = (const int*)d_in[2];
    float*       out     = (float*)d_out;

    const int grid = N * (H / BAND) * (W / CT);   // 512 blocks
    lcl_xyz_kernel<<<grid, BLK, 0, stream>>>(xyz, softmax, mask, out);
}

// Round 13
// 193.092 us; speedup vs baseline: 1.2531x; 1.2531x over previous
//
#include <hip/hip_runtime.h>

// Problem constants (from reference)
constexpr int N = 2;
constexpr int C = 20;
constexpr int H = 64;
constexpr int W = 2048;          // power of two -> wrap via & (W-1)
constexpr int HW = H * W;

constexpr int BLK   = 512;       // 8 waves; wave v owns output row h0+v (128 cols)
constexpr int BAND  = 8;         // output rows per block
constexpr int CT    = 128;       // output cols per block
constexpr int SROWS = 12;        // staged rows per slab (8 band + 4 halo, clamped)
constexpr int SCOLS = 136;       // staged cols (wc0-4 .. wc0+131), 34 float4
constexpr int ITEMS = 408;       // float4 items per slab = 12*34
constexpr int SLABF = SROWS * SCOLS;   // 1632 floats
constexpr int SLABB = SLABF * 4;       // 6528 bytes (= 408*16, 16B aligned)
constexpr int NSLAB = 4;
// LDS = 4 slabs x 6528 B = 26112 B. grid = N*(H/8)*(W/128) = 2*8*16 = 256 blocks
// = exactly 1 block/CU (8 waves/CU), perfectly balanced.

#define GLDS16(g, l)                                                        \
    __builtin_amdgcn_global_load_lds(                                       \
        (const __attribute__((address_space(1))) void*)(g),                 \
        (__attribute__((address_space(3))) void*)(l), 16, 0, 0)

__global__ __launch_bounds__(BLK, 2)
void lcl_xyz_kernel(const float* __restrict__ xyz,
                    const float* __restrict__ softmax,
                    const int* __restrict__ mask,
                    float* __restrict__ out) {
    __shared__ __align__(16) float lds[NSLAB * SLABF];   // 26112 B

    const int t  = threadIdx.x;
    const int l  = t & 63;                 // lane
    const int wv = t >> 6;                 // wave 0..7 = output row within band

    // XCD swizzle: XCD (bid%8) owns 32 consecutive works = 2 full bands
    // (all col tiles) -> band halo rows shared within one XCD L2.
    const int bid  = blockIdx.x;
    const int work = (bid & 7) * 32 + (bid >> 3);   // bijective over [0,256)
    const int ct   = work & 15;
    const int nb   = work >> 4;            // n*8 + band
    const int n    = nb >> 3;
    const int band = nb & 7;
    const int h0   = band * BAND;
    const int wc0  = ct * CT;

    const int orow = h0 + wv;              // this wave's output row
    const int oc   = wc0 + 2 * l;          // thread's first output col (even)

    const float* xb  = xyz + (size_t)(n * 3 + 0) * HW;
    const float* yb  = xyz + (size_t)(n * 3 + 1) * HW;
    const float* zb  = xyz + (size_t)(n * 3 + 2) * HW;
    const int*   mb  = mask + (size_t)n * HW;
    const float* smb = softmax + (size_t)n * C * HW;

    // ---- Weight phase: direct global float2 loads (one-time, no LDS, no sync) ----
    int  rowoff[5];
    bool hv[5];
    #pragma unroll
    for (int r = 0; r < 5; ++r) {
        int hh = orow - 2 + r;
        hv[r] = (unsigned)hh < (unsigned)H;
        rowoff[r] = min(max(hh, 0), H - 1) * W;
    }
    const int cm = (oc - 2) & (W - 1);
    const int c0 = oc;
    const int cp = (oc + 2) & (W - 1);

    const float2 cx2 = *(const float2*)(xb + orow * W + c0);
    const float2 cy2 = *(const float2*)(yb + orow * W + c0);
    const float2 cz2 = *(const float2*)(zb + orow * W + c0);

    float wa[5][5], wb_[5][5];
    #pragma unroll
    for (int r = 0; r < 5; ++r) {
        float2 xm = *(const float2*)(xb + rowoff[r] + cm);
        float2 x0 = *(const float2*)(xb + rowoff[r] + c0);
        float2 xp = *(const float2*)(xb + rowoff[r] + cp);
        float2 ym = *(const float2*)(yb + rowoff[r] + cm);
        float2 y0 = *(const float2*)(yb + rowoff[r] + c0);
        float2 yp = *(const float2*)(yb + rowoff[r] + cp);
        float2 zm = *(const float2*)(zb + rowoff[r] + cm);
        float2 z0 = *(const float2*)(zb + rowoff[r] + c0);
        float2 zp = *(const float2*)(zb + rowoff[r] + cp);
        int2   km = *(const int2*)(mb + rowoff[r] + cm);
        int2   k0 = *(const int2*)(mb + rowoff[r] + c0);
        int2   kp = *(const int2*)(mb + rowoff[r] + cp);

        const float xv[6] = {xm.x, xm.y, x0.x, x0.y, xp.x, xp.y};
        const float yv[6] = {ym.x, ym.y, y0.x, y0.y, yp.x, yp.y};
        const float zv[6] = {zm.x, zm.y, z0.x, z0.y, zp.x, zp.y};
        const int   mv[6] = {km.x, km.y, k0.x, k0.y, kp.x, kp.y};

        #pragma unroll
        for (int j = 0; j < 5; ++j) {
            float dx = xv[j] - cx2.x, dy = yv[j] - cy2.x, dz = zv[j] - cz2.x;
            float d2 = dx * dx + dy * dy + dz * dz;
            wa[r][j] = (hv[r] && mv[j]) ? d2 : 1e30f;       // masked -> exp -> 0
            float ex = xv[j + 1] - cx2.y, ey = yv[j + 1] - cy2.y, ez = zv[j + 1] - cz2.y;
            float e2 = ex * ex + ey * ey + ez * ez;
            wb_[r][j] = (hv[r] && mv[j + 1]) ? e2 : 1e30f;
        }
    }
    #pragma unroll
    for (int r = 0; r < 5; ++r)
        #pragma unroll
        for (int j = 0; j < 5; ++j) {
            wa[r][j]  = __expf(-0.5f * wa[r][j]);
            wb_[r][j] = __expf(-0.5f * wb_[r][j]);
        }
    // All weight loads consumed above -> retired; vmcnt stream will hold only slabs.

    // ---- Block-cooperative staging tuple: 1 global_load_lds per thread per class.
    //      Slab rows h0-2..h0+9 (clamped), cols wc0-4..wc0+131. Linear LDS dest.
    const bool doload = (t < ITEMS);
    int so = 0;
    {
        int r  = t / 34;
        int k  = t - 34 * r;
        int sr = min(max(h0 - 2 + r, 0), H - 1);
        so = sr * W + ((wc0 - 4 + 4 * k) & (W - 1));
    }
    const int   lcol = 2 * l + 2;          // local col of leftmost tap
    const float* wrow = lds + wv * SCOLS;  // wave's row base within a slab

    // ---- Prime pipeline: classes 0..2 into slabs 0..2 (<=3 loads/thread) ----
    __builtin_amdgcn_sched_barrier(0);
    #pragma unroll
    for (int pc = 0; pc < 3; ++pc) {
        if (doload)
            GLDS16(smb + (size_t)pc * HW + so, (char*)lds + pc * SLABB + t * 16);
    }

    float2 acc[C];

    // STEP: wait own vmcnt (counted; never 0 until the end) + barrier (all waves'
    // class-K loads then complete), issue class K+3 into slab (K+3)&3 (freed by
    // the barrier: all waves finished reading it in STEP K-1), compute class K.
#define STEP(K, KLIT)                                                        \
    do {                                                                     \
        asm volatile("s_waitcnt vmcnt(" #KLIT ")\n\ts_barrier" ::: "memory");\
        if ((K) + 3 < C && doload)                                           \
            GLDS16(smb + (size_t)((K) + 3) * HW + so,                        \
                   (char*)lds + (((K) + 3) & 3) * SLABB + t * 16);           \
        const float* rw = wrow + ((K) & 3) * SLABF + lcol;                   \
        float a0 = 0.f, a1 = 0.f;                                            \
        _Pragma("unroll")                                                    \
        for (int r = 0; r < 5; ++r) {                                        \
            const float* q = rw + r * SCOLS;                                 \
            float2 u0 = *(const float2*)(q);                                 \
            float2 u1 = *(const float2*)(q + 2);                             \
            float2 u2 = *(const float2*)(q + 4);                             \
            a0 = fmaf(wa[r][0], u0.x, a0);  a0 = fmaf(wa[r][1], u0.y, a0);   \
            a0 = fmaf(wa[r][2], u1.x, a0);  a0 = fmaf(wa[r][3], u1.y, a0);   \
            a0 = fmaf(wa[r][4], u2.x, a0);                                   \
            a1 = fmaf(wb_[r][0], u0.y, a1); a1 = fmaf(wb_[r][1], u1.x, a1);  \
            a1 = fmaf(wb_[r][2], u1.y, a1); a1 = fmaf(wb_[r][3], u2.x, a1);  \
            a1 = fmaf(wb_[r][4], u2.y, a1);                                  \
        }                                                                    \
        acc[K].x = a0; acc[K].y = a1;                                        \
    } while (0)

    STEP( 0, 2);  STEP( 1, 2);  STEP( 2, 2);  STEP( 3, 2);  STEP( 4, 2);
    STEP( 5, 2);  STEP( 6, 2);  STEP( 7, 2);  STEP( 8, 2);  STEP( 9, 2);
    STEP(10, 2);  STEP(11, 2);  STEP(12, 2);  STEP(13, 2);  STEP(14, 2);
    STEP(15, 2);  STEP(16, 2);  STEP(17, 2);  STEP(18, 1);  STEP(19, 0);
#undef STEP

    // ---- Epilogue: coalesced float2 stores (20 classes) ----
    float* ob = out + (size_t)n * C * HW + (size_t)orow * W + oc;
    #pragma unroll
    for (int c = 0; c < C; ++c)
        *(float2*)(ob + (size_t)c * HW) = acc[c];
}

extern "C" void kernel_launch(void* const* d_in, const int* in_sizes, int n_in,
                              void* d_out, int out_size, void* d_ws, size_t ws_size,
                              hipStream_t stream) {
    const float* xyz     = (const float*)d_in[0];
    const float* softmax = (const float*)d_in[1];
    const int*   mask    = (const int*)d_in[2];
    float*       out     = (float*)d_out;

    const int grid = N * (H / BAND) * (W / CT);   // 256 blocks
    lcl_xyz_kernel<<<grid, BLK, 0, stream>>>(xyz, softmax, mask, out);
}

// Round 14
// 192.278 us; speedup vs baseline: 1.2584x; 1.0042x over previous
//
#include <hip/hip_runtime.h>

// Problem constants (from reference)
constexpr int N = 2;
constexpr int C = 20;
constexpr int H = 64;
constexpr int W = 2048;          // power of two -> wrap via & (W-1)
constexpr int HW = H * W;

constexpr int BLK   = 512;       // 8 waves; wave v owns output row h0+v (128 cols)
constexpr int BAND  = 8;         // output rows per block
constexpr int CT    = 128;       // output cols per block
constexpr int SROWS = 12;        // staged rows per slab (8 band + 4 halo, clamped)
constexpr int SCOLS = 136;       // staged cols (wc0-4 .. wc0+131), 34 float4
constexpr int ITEMS = 408;       // float4 items per slab = 12*34
constexpr int SLABF = SROWS * SCOLS;   // 1632 floats
constexpr int SLABB = SLABF * 4;       // 6528 bytes (= 408*16, 16B aligned)
constexpr int NSLAB = 4;
// LDS = 4 slabs x 6528 B = 26112 B. grid = N*(H/8)*(W/128) = 2*8*16 = 256 blocks
// = exactly 1 block/CU (8 waves/CU).

#define GLDS16(g, l)                                                        \
    __builtin_amdgcn_global_load_lds(                                       \
        (const __attribute__((address_space(1))) void*)(g),                 \
        (__attribute__((address_space(3))) void*)(l), 16, 0, 0)

// (512,1): no VGPR cap (512/wave available) -> ~140 live values fit, ZERO spill.
// R10-R13's 64/128-VGPR caps spilled wa/wb/acc to scratch; the 150-400 MB
// FETCH/WRITE explosions were spill traffic, not locality loss.
__global__ __launch_bounds__(BLK, 1)
void lcl_xyz_kernel(const float* __restrict__ xyz,
                    const float* __restrict__ softmax,
                    const int* __restrict__ mask,
                    float* __restrict__ out) {
    __shared__ __align__(16) float lds[NSLAB * SLABF];   // 26112 B

    const int t  = threadIdx.x;
    const int l  = t & 63;                 // lane
    const int wv = t >> 6;                 // wave 0..7 = output row within band

    // XCD swizzle: XCD (bid%8) owns 32 consecutive works = 2 full bands
    // (all col tiles) -> band halo rows shared within one XCD L2.
    const int bid  = blockIdx.x;
    const int work = (bid & 7) * 32 + (bid >> 3);   // bijective over [0,256)
    const int ct   = work & 15;
    const int nb   = work >> 4;            // n*8 + band
    const int n    = nb >> 3;
    const int band = nb & 7;
    const int h0   = band * BAND;
    const int wc0  = ct * CT;

    const int orow = h0 + wv;              // this wave's output row
    const int oc   = wc0 + 2 * l;          // thread's first output col (even)

    const float* xb  = xyz + (size_t)(n * 3 + 0) * HW;
    const float* yb  = xyz + (size_t)(n * 3 + 1) * HW;
    const float* zb  = xyz + (size_t)(n * 3 + 2) * HW;
    const int*   mb  = mask + (size_t)n * HW;
    const float* smb = softmax + (size_t)n * C * HW;

    // ---- Weight phase: direct global float2 loads (one-time, no LDS, no sync) ----
    int  rowoff[5];
    bool hv[5];
    #pragma unroll
    for (int r = 0; r < 5; ++r) {
        int hh = orow - 2 + r;
        hv[r] = (unsigned)hh < (unsigned)H;
        rowoff[r] = min(max(hh, 0), H - 1) * W;
    }
    const int cm = (oc - 2) & (W - 1);
    const int c0 = oc;
    const int cp = (oc + 2) & (W - 1);

    const float2 cx2 = *(const float2*)(xb + orow * W + c0);
    const float2 cy2 = *(const float2*)(yb + orow * W + c0);
    const float2 cz2 = *(const float2*)(zb + orow * W + c0);

    float wa[5][5], wb_[5][5];
    #pragma unroll
    for (int r = 0; r < 5; ++r) {
        float2 xm = *(const float2*)(xb + rowoff[r] + cm);
        float2 x0 = *(const float2*)(xb + rowoff[r] + c0);
        float2 xp = *(const float2*)(xb + rowoff[r] + cp);
        float2 ym = *(const float2*)(yb + rowoff[r] + cm);
        float2 y0 = *(const float2*)(yb + rowoff[r] + c0);
        float2 yp = *(const float2*)(yb + rowoff[r] + cp);
        float2 zm = *(const float2*)(zb + rowoff[r] + cm);
        float2 z0 = *(const float2*)(zb + rowoff[r] + c0);
        float2 zp = *(const float2*)(zb + rowoff[r] + cp);
        int2   km = *(const int2*)(mb + rowoff[r] + cm);
        int2   k0 = *(const int2*)(mb + rowoff[r] + c0);
        int2   kp = *(const int2*)(mb + rowoff[r] + cp);

        const float xv[6] = {xm.x, xm.y, x0.x, x0.y, xp.x, xp.y};
        const float yv[6] = {ym.x, ym.y, y0.x, y0.y, yp.x, yp.y};
        const float zv[6] = {zm.x, zm.y, z0.x, z0.y, zp.x, zp.y};
        const int   mv[6] = {km.x, km.y, k0.x, k0.y, kp.x, kp.y};

        #pragma unroll
        for (int j = 0; j < 5; ++j) {
            float dx = xv[j] - cx2.x, dy = yv[j] - cy2.x, dz = zv[j] - cz2.x;
            float d2 = dx * dx + dy * dy + dz * dz;
            wa[r][j] = (hv[r] && mv[j]) ? d2 : 1e30f;       // masked -> exp -> 0
            float ex = xv[j + 1] - cx2.y, ey = yv[j + 1] - cy2.y, ez = zv[j + 1] - cz2.y;
            float e2 = ex * ex + ey * ey + ez * ez;
            wb_[r][j] = (hv[r] && mv[j + 1]) ? e2 : 1e30f;
        }
    }
    #pragma unroll
    for (int r = 0; r < 5; ++r)
        #pragma unroll
        for (int j = 0; j < 5; ++j) {
            wa[r][j]  = __expf(-0.5f * wa[r][j]);
            wb_[r][j] = __expf(-0.5f * wb_[r][j]);
        }
    // All weight loads consumed above -> retired; vmcnt stream will hold only slabs.

    // ---- Block-cooperative staging tuple: 1 global_load_lds per thread per class.
    //      Slab rows h0-2..h0+9 (clamped), cols wc0-4..wc0+131. Linear LDS dest.
    const bool doload = (t < ITEMS);
    int so = 0;
    {
        int r  = t / 34;
        int k  = t - 34 * r;
        int sr = min(max(h0 - 2 + r, 0), H - 1);
        so = sr * W + ((wc0 - 4 + 4 * k) & (W - 1));
    }
    const int   lcol = 2 * l + 2;          // local col of leftmost tap
    const float* wrow = lds + wv * SCOLS;  // wave's row base within a slab

    // ---- Prime pipeline: classes 0..2 into slabs 0..2 (<=3 loads/thread) ----
    __builtin_amdgcn_sched_barrier(0);
    #pragma unroll
    for (int pc = 0; pc < 3; ++pc) {
        if (doload)
            GLDS16(smb + (size_t)pc * HW + so, (char*)lds + pc * SLABB + t * 16);
    }

    float2 acc[C];

    // STEP: wait own vmcnt (counted; never 0 until the end) + barrier (all waves'
    // class-K loads then complete), issue class K+3 into slab (K+3)&3 (freed by
    // the barrier: all waves finished reading it in STEP K-1), compute class K.
#define STEP(K, KLIT)                                                        \
    do {                                                                     \
        asm volatile("s_waitcnt vmcnt(" #KLIT ")\n\ts_barrier" ::: "memory");\
        if ((K) + 3 < C && doload)                                           \
            GLDS16(smb + (size_t)((K) + 3) * HW + so,                        \
                   (char*)lds + (((K) + 3) & 3) * SLABB + t * 16);           \
        const float* rw = wrow + ((K) & 3) * SLABF + lcol;                   \
        float a0 = 0.f, a1 = 0.f;                                            \
        _Pragma("unroll")                                                    \
        for (int r = 0; r < 5; ++r) {                                        \
            const float* q = rw + r * SCOLS;                                 \
            float2 u0 = *(const float2*)(q);                                 \
            float2 u1 = *(const float2*)(q + 2);                             \
            float2 u2 = *(const float2*)(q + 4);                             \
            a0 = fmaf(wa[r][0], u0.x, a0);  a0 = fmaf(wa[r][1], u0.y, a0);   \
            a0 = fmaf(wa[r][2], u1.x, a0);  a0 = fmaf(wa[r][3], u1.y, a0);   \
            a0 = fmaf(wa[r][4], u2.x, a0);                                   \
            a1 = fmaf(wb_[r][0], u0.y, a1); a1 = fmaf(wb_[r][1], u1.x, a1);  \
            a1 = fmaf(wb_[r][2], u1.y, a1); a1 = fmaf(wb_[r][3], u2.x, a1);  \
            a1 = fmaf(wb_[r][4], u2.y, a1);                                  \
        }                                                                    \
        acc[K].x = a0; acc[K].y = a1;                                        \
    } while (0)

    STEP( 0, 2);  STEP( 1, 2);  STEP( 2, 2);  STEP( 3, 2);  STEP( 4, 2);
    STEP( 5, 2);  STEP( 6, 2);  STEP( 7, 2);  STEP( 8, 2);  STEP( 9, 2);
    STEP(10, 2);  STEP(11, 2);  STEP(12, 2);  STEP(13, 2);  STEP(14, 2);
    STEP(15, 2);  STEP(16, 2);  STEP(17, 2);  STEP(18, 1);  STEP(19, 0);
#undef STEP

    // ---- Epilogue: coalesced float2 stores (20 classes) ----
    float* ob = out + (size_t)n * C * HW + (size_t)orow * W + oc;
    #pragma unroll
    for (int c = 0; c < C; ++c)
        *(float2*)(ob + (size_t)c * HW) = acc[c];
}

extern "C" void kernel_launch(void* const* d_in, const int* in_sizes, int n_in,
                              void* d_out, int out_size, void* d_ws, size_t ws_size,
                              hipStream_t stream) {
    const float* xyz     = (const float*)d_in[0];
    const float* softmax = (const float*)d_in[1];
    const int*   mask    = (const int*)d_in[2];
    float*       out     = (float*)d_out;

    const int grid = N * (H / BAND) * (W / CT);   // 256 blocks
    lcl_xyz_kernel<<<grid, BLK, 0, stream>>>(xyz, softmax, mask, out);
}

// Round 15
// 29.311 us; speedup vs baseline: 8.2553x; 6.5600x over previous
//
#include <hip/hip_runtime.h>

// Problem constants (from reference)
constexpr int N = 2;
constexpr int C = 20;
constexpr int H = 64;
constexpr int W = 2048;          // power of two -> wrap via & (W-1)
constexpr int HW = H * W;

constexpr int BLK   = 512;       // 8 waves: waves 0-3 -> row h0, waves 4-7 -> row h0+1
constexpr int CT    = 512;       // cols per block
constexpr int SROWS = 6;         // staged rows: h0-2 .. h0+3 (clamped)
constexpr int SCOLS = 520;       // staged cols: wc0-4 .. wc0+515
constexpr int F4    = 130;       // float4 items per staged row
constexpr int ITEMS = 780;       // real float4 items per slab (6*130)
constexpr int SLABPF = 4096;     // padded slab stride (floats) = 16384 B
constexpr int SLABPB = 16384;
// LDS = 3 slabs x 16384 B = 49152 B. grid = N*(H/2)*(W/512) = 2*32*4 = 256 blocks
// = 1 block/CU = 8 waves/CU (same TLP as R8, 40% less staging traffic).

#define GLDS16(g, l)                                                        \
    __builtin_amdgcn_global_load_lds(                                       \
        (const __attribute__((address_space(1))) void*)(g),                 \
        (__attribute__((address_space(3))) void*)(l), 16, 0, 0)

__global__ __launch_bounds__(BLK, 2)
void lcl_xyz_kernel(const float* __restrict__ xyz,
                    const float* __restrict__ softmax,
                    const int* __restrict__ mask,
                    float* __restrict__ out) {
    __shared__ __align__(16) float lds[3 * SLABPF];   // 49152 B

    const int t = threadIdx.x;

    // XCD swizzle: XCD (bid%8) owns 32 consecutive works = 8 contiguous h-pairs
    // (16 rows) of one n -> halo rows shared within one XCD L2.
    const int bid  = blockIdx.x;
    const int work = (bid & 7) * 32 + (bid >> 3);   // bijective over [0,256)
    const int ct   = work & 3;
    const int hp   = (work >> 2) & 31;
    const int n    = work >> 7;
    const int h0   = hp * 2;
    const int wc0  = ct * CT;

    const int rr0  = t >> 8;               // 0: row h0 (waves 0-3), 1: row h0+1
    const int cp_  = t & 255;              // col-pair index
    const int orow = h0 + rr0;
    const int oc   = wc0 + 2 * cp_;        // thread's first output col (even)

    const float* xb  = xyz + (size_t)(n * 3 + 0) * HW;
    const float* yb  = xyz + (size_t)(n * 3 + 1) * HW;
    const float* zb  = xyz + (size_t)(n * 3 + 2) * HW;
    const int*   mb  = mask + (size_t)n * HW;
    const float* smb = softmax + (size_t)n * C * HW;

    // ---- Weight phase: direct global float2 loads (R9-proven path) ----
    int  rowoff[5];
    bool hv[5];
    #pragma unroll
    for (int r = 0; r < 5; ++r) {
        int hh = orow - 2 + r;
        hv[r] = (unsigned)hh < (unsigned)H;
        rowoff[r] = min(max(hh, 0), H - 1) * W;
    }
    const int cm = (oc - 2) & (W - 1);
    const int c0 = oc;
    const int cp = (oc + 2) & (W - 1);

    const float2 cx2 = *(const float2*)(xb + orow * W + c0);
    const float2 cy2 = *(const float2*)(yb + orow * W + c0);
    const float2 cz2 = *(const float2*)(zb + orow * W + c0);

    float wa[5][5], wb_[5][5];
    #pragma unroll
    for (int r = 0; r < 5; ++r) {
        float2 xm = *(const float2*)(xb + rowoff[r] + cm);
        float2 x0 = *(const float2*)(xb + rowoff[r] + c0);
        float2 xp = *(const float2*)(xb + rowoff[r] + cp);
        float2 ym = *(const float2*)(yb + rowoff[r] + cm);
        float2 y0 = *(const float2*)(yb + rowoff[r] + c0);
        float2 yp = *(const float2*)(yb + rowoff[r] + cp);
        float2 zm = *(const float2*)(zb + rowoff[r] + cm);
        float2 z0 = *(const float2*)(zb + rowoff[r] + c0);
        float2 zp = *(const float2*)(zb + rowoff[r] + cp);
        int2   km = *(const int2*)(mb + rowoff[r] + cm);
        int2   k0 = *(const int2*)(mb + rowoff[r] + c0);
        int2   kp = *(const int2*)(mb + rowoff[r] + cp);

        const float xv[6] = {xm.x, xm.y, x0.x, x0.y, xp.x, xp.y};
        const float yv[6] = {ym.x, ym.y, y0.x, y0.y, yp.x, yp.y};
        const float zv[6] = {zm.x, zm.y, z0.x, z0.y, zp.x, zp.y};
        const int   mv[6] = {km.x, km.y, k0.x, k0.y, kp.x, kp.y};

        #pragma unroll
        for (int j = 0; j < 5; ++j) {
            float dx = xv[j] - cx2.x, dy = yv[j] - cy2.x, dz = zv[j] - cz2.x;
            float d2 = dx * dx + dy * dy + dz * dz;
            wa[r][j] = (hv[r] && mv[j]) ? d2 : 1e30f;       // masked -> exp -> 0
            float ex = xv[j + 1] - cx2.y, ey = yv[j + 1] - cy2.y, ez = zv[j + 1] - cz2.y;
            float e2 = ex * ex + ey * ey + ez * ez;
            wb_[r][j] = (hv[r] && mv[j + 1]) ? e2 : 1e30f;
        }
    }
    #pragma unroll
    for (int r = 0; r < 5; ++r)
        #pragma unroll
        for (int j = 0; j < 5; ++j) {
            wa[r][j]  = __expf(-0.5f * wa[r][j]);
            wb_[r][j] = __expf(-0.5f * wb_[r][j]);
        }

    // ---- Staging tuples: uniform 2 glds/thread/class (wrap keeps counts even).
    //      Slab rows h0-2..h0+3 (clamped), cols wc0-4..wc0+515. Linear LDS dest.
    int so0, so1;
    {
        int r0 = t / F4, k0 = t - F4 * r0;
        so0 = min(max(h0 - 2 + r0, 0), H - 1) * W + ((wc0 - 4 + 4 * k0) & (W - 1));
        int i1 = (t < ITEMS - BLK) ? (BLK + t) : (t - (ITEMS - BLK));  // real : dup
        int r1 = i1 / F4, k1 = i1 - F4 * r1;
        so1 = min(max(h0 - 2 + r1, 0), H - 1) * W + ((wc0 - 4 + 4 * k1) & (W - 1));
    }
    const int dst0 = t * 16;
    const int dst1 = (BLK + t) * 16;        // t >= 268 lands in pad (never read)
    const int lcol = 2 * cp_ + 2;           // slab col of leftmost tap
    const float* wbase = lds + rr0 * SCOLS + lcol;   // + slab*SLABPF + r*SCOLS

    // Drain weight-phase loads so the vmcnt stream holds ONLY staging glds.
    asm volatile("s_waitcnt vmcnt(0)" ::: "memory");

    // ---- Prime pipeline: classes 0,1 into slabs 0,1 (4 glds in flight) ----
    GLDS16(smb + so0, (char*)lds + dst0);
    GLDS16(smb + so1, (char*)lds + dst1);
    GLDS16(smb + (size_t)HW + so0, (char*)lds + SLABPB + dst0);
    GLDS16(smb + (size_t)HW + so1, (char*)lds + SLABPB + dst1);

    float2 acc[C];

    // STEP: counted vmcnt (class K's 2 glds retired) + barrier (all waves), then
    // issue class K+2 into slab (K+2)%3 (= slab read in STEP K-1, freed by the
    // barrier), then compute class K from slab K%3.
#define STEP(K, KLIT)                                                        \
    do {                                                                     \
        asm volatile("s_waitcnt vmcnt(" #KLIT ")\n\ts_barrier" ::: "memory");\
        if ((K) + 2 < C) {                                                   \
            const float* scn = smb + (size_t)((K) + 2) * HW;                 \
            GLDS16(scn + so0, (char*)lds + (((K) + 2) % 3) * SLABPB + dst0); \
            GLDS16(scn + so1, (char*)lds + (((K) + 2) % 3) * SLABPB + dst1); \
        }                                                                    \
        const float* rw = wbase + ((K) % 3) * SLABPF;                        \
        float a0 = 0.f, a1 = 0.f;                                            \
        _Pragma("unroll")                                                    \
        for (int r = 0; r < 5; ++r) {                                        \
            const float* q = rw + r * SCOLS;                                 \
            float2 u0 = *(const float2*)(q);                                 \
            float2 u1 = *(const float2*)(q + 2);                             \
            float2 u2 = *(const float2*)(q + 4);                             \
            a0 = fmaf(wa[r][0], u0.x, a0);  a0 = fmaf(wa[r][1], u0.y, a0);   \
            a0 = fmaf(wa[r][2], u1.x, a0);  a0 = fmaf(wa[r][3], u1.y, a0);   \
            a0 = fmaf(wa[r][4], u2.x, a0);                                   \
            a1 = fmaf(wb_[r][0], u0.y, a1); a1 = fmaf(wb_[r][1], u1.x, a1);  \
            a1 = fmaf(wb_[r][2], u1.y, a1); a1 = fmaf(wb_[r][3], u2.x, a1);  \
            a1 = fmaf(wb_[r][4], u2.y, a1);                                  \
        }                                                                    \
        acc[K].x = a0; acc[K].y = a1;                                        \
    } while (0)

    STEP( 0, 2);  STEP( 1, 2);  STEP( 2, 2);  STEP( 3, 2);  STEP( 4, 2);
    STEP( 5, 2);  STEP( 6, 2);  STEP( 7, 2);  STEP( 8, 2);  STEP( 9, 2);
    STEP(10, 2);  STEP(11, 2);  STEP(12, 2);  STEP(13, 2);  STEP(14, 2);
    STEP(15, 2);  STEP(16, 2);  STEP(17, 2);  STEP(18, 2);  STEP(19, 0);
#undef STEP

    // ---- Epilogue: coalesced float2 stores (20 classes) ----
    float* ob = out + (size_t)n * C * HW + (size_t)orow * W + oc;
    #pragma unroll
    for (int c = 0; c < C; ++c)
        *(float2*)(ob + (size_t)c * HW) = acc[c];
}

extern "C" void kernel_launch(void* const* d_in, const int* in_sizes, int n_in,
                              void* d_out, int out_size, void* d_ws, size_t ws_size,
                              hipStream_t stream) {
    const float* xyz     = (const float*)d_in[0];
    const float* softmax = (const float*)d_in[1];
    const int*   mask    = (const int*)d_in[2];
    float*       out     = (float*)d_out;

    const int grid = N * (H / 2) * (W / CT);   // 256 blocks
    lcl_xyz_kernel<<<grid, BLK, 0, stream>>>(xyz, softmax, mask, out);
}

// Round 16
// 26.223 us; speedup vs baseline: 9.2272x; 1.1177x over previous
//
#include <hip/hip_runtime.h>

// Problem constants (from reference)
constexpr int N = 2;
constexpr int C = 20;
constexpr int H = 64;
constexpr int W = 2048;          // power of two -> wrap via & (W-1)
constexpr int HW = H * W;

constexpr int BLK   = 256;       // 4 waves; each wave owns 64 cols (OPT=1)
constexpr int TILE  = 256;       // cols per block
constexpr int ROWF  = 72;        // slab floats per row (W0-4 .. W0+67)
constexpr int RITEMS = 90;       // real float4 items per slab (5 rows x 18)
constexpr int SLABF = 512;       // padded slab stride (floats) = 2048 B
constexpr int SLABB = 2048;
// LDS = 4 waves x 4 slabs x 2048 B = 32 KB -> 4 blocks/CU (128 KB of 160).
// grid = 2*64*8 = 1024 blocks -> 4096 waves -> 16 waves/CU = 4/SIMD (2x R9).

#define GLDS16(g, l)                                                        \
    __builtin_amdgcn_global_load_lds(                                       \
        (const __attribute__((address_space(1))) void*)(g),                 \
        (__attribute__((address_space(3))) void*)(l), 16, 0, 0)

__global__ __launch_bounds__(BLK, 4)   // VGPR cap 128; est. use ~90 -> no spill
void lcl_xyz_kernel(const float* __restrict__ xyz,
                    const float* __restrict__ softmax,
                    const int* __restrict__ mask,
                    float* __restrict__ out) {
    __shared__ __align__(16) float lds[4 * 4 * SLABF];   // 32768 B

    const int t  = threadIdx.x;
    const int l  = t & 63;                 // lane
    const int wv = t >> 6;                 // wave 0..3

    // XCD swizzle (R6's measured-good scheme at 1024 blocks): XCD (bid%8)
    // owns 128 consecutive works = 16 contiguous (n*64+h) rows on one L2.
    const int bid  = blockIdx.x;
    const int work = (bid & 7) * 128 + (bid >> 3);   // bijective over [0,1024)
    const int nh   = work >> 3;
    const int bw   = work & 7;
    const int n    = nh >> 6;
    const int h    = nh & 63;
    const int W0   = bw * TILE + 64 * wv;  // wave strip base col
    const int oc   = W0 + l;               // this thread's single output col
    const int p    = l & 1;                // col parity -> weight slot shift

    const float* xb  = xyz + (size_t)(n * 3 + 0) * HW;
    const float* yb  = xyz + (size_t)(n * 3 + 1) * HW;
    const float* zb  = xyz + (size_t)(n * 3 + 2) * HW;
    const int*   mb  = mask + (size_t)n * HW;
    const float* smb = softmax + (size_t)n * C * HW;

    int  rowoff[5];
    bool hv[5];
    #pragma unroll
    for (int r = 0; r < 5; ++r) {
        int hh = h - 2 + r;
        hv[r] = (unsigned)hh < (unsigned)H;
        rowoff[r] = min(max(hh, 0), H - 1) * W;
    }

    // ---- Weight phase: 6-slot rows. Slot k holds the gaussian weight for
    //      data float f_k at col (oc-2-p+k); tap j sits at slot j+p; the
    //      off-window slot (k=0 if p, k=5 if !p) is zeroed. ALL indices static.
    const float cx = xb[h * W + oc];
    const float cy = yb[h * W + oc];
    const float cz = zb[h * W + oc];

    const int sc0 = (oc - 2 - p) & (W - 1);      // even, 8B-aligned
    const int sc1 = (oc     - p) & (W - 1);
    const int sc2 = (oc + 2 - p) & (W - 1);

    float wgt[5][6];
    #pragma unroll
    for (int r = 0; r < 5; ++r) {
        float2 x0 = *(const float2*)(xb + rowoff[r] + sc0);
        float2 x1 = *(const float2*)(xb + rowoff[r] + sc1);
        float2 x2 = *(const float2*)(xb + rowoff[r] + sc2);
        float2 y0 = *(const float2*)(yb + rowoff[r] + sc0);
        float2 y1 = *(const float2*)(yb + rowoff[r] + sc1);
        float2 y2 = *(const float2*)(yb + rowoff[r] + sc2);
        float2 z0 = *(const float2*)(zb + rowoff[r] + sc0);
        float2 z1 = *(const float2*)(zb + rowoff[r] + sc1);
        float2 z2 = *(const float2*)(zb + rowoff[r] + sc2);
        int2   m0 = *(const int2*)(mb + rowoff[r] + sc0);
        int2   m1 = *(const int2*)(mb + rowoff[r] + sc1);
        int2   m2 = *(const int2*)(mb + rowoff[r] + sc2);

        const float xv[6] = {x0.x, x0.y, x1.x, x1.y, x2.x, x2.y};
        const float yv[6] = {y0.x, y0.y, y1.x, y1.y, y2.x, y2.y};
        const float zv[6] = {z0.x, z0.y, z1.x, z1.y, z2.x, z2.y};
        const int   mv[6] = {m0.x, m0.y, m1.x, m1.y, m2.x, m2.y};

        #pragma unroll
        for (int k = 0; k < 6; ++k) {
            float dx = xv[k] - cx, dy = yv[k] - cy, dz = zv[k] - cz;
            float d2 = dx * dx + dy * dy + dz * dz;
            d2 = (hv[r] && mv[k]) ? d2 : 1e30f;   // masked -> exp -> 0
            wgt[r][k] = __expf(-0.5f * d2);
        }
        wgt[r][0] = p ? 0.0f : wgt[r][0];   // p=1: slot0 outside window
        wgt[r][5] = p ? wgt[r][5] : 0.0f;   // p=0: slot5 outside window
    }

    // ---- Per-wave staging tuples: 2 glds/class (uniform; lanes >= 26 dup
    //      item 0 into the slab pad region, never read).
    int so0, so1;
    {
        int r0 = l / 18, k0 = l - 18 * r0;
        so0 = rowoff[r0] + ((W0 - 4 + 4 * k0) & (W - 1));
        int i1 = (64 + l < RITEMS) ? 64 + l : 0;
        int r1 = i1 / 18, k1 = i1 - 18 * r1;
        so1 = rowoff[r1] + ((W0 - 4 + 4 * k1) & (W - 1));
    }
    char*        ldst  = (char*)lds + wv * (4 * SLABB) + l * 16;
    const float* wbase = lds + wv * (4 * SLABF);
    const int    rb    = l + 2 - p;        // even slab float offset of slot 0

    // Drain weight-phase loads -> vmcnt stream holds ONLY staging glds.
    asm volatile("s_waitcnt vmcnt(0)" ::: "memory");

    // ---- Prime: classes 0..3 into slabs 0..3 (8 glds in flight) ----
    #pragma unroll
    for (int pc = 0; pc < 4; ++pc) {
        const float* sc = smb + (size_t)pc * HW;
        GLDS16(sc + so0, ldst + pc * SLABB);
        GLDS16(sc + so1, ldst + pc * SLABB + 1024);
    }

    float acc[C];

    // Per-wave STEP: counted vmcnt (private slab -> no barrier), compute class
    // K from slab K&3, refill that slab with class K+4.
#define STEP(K, KLIT)                                                        \
    do {                                                                     \
        asm volatile("s_waitcnt vmcnt(" #KLIT ")" ::: "memory");             \
        const float* rw = wbase + ((K) & 3) * SLABF + rb;                    \
        float a = 0.0f;                                                      \
        _Pragma("unroll")                                                    \
        for (int r = 0; r < 5; ++r) {                                        \
            const float* q = rw + r * ROWF;                                  \
            float2 u0 = *(const float2*)(q);                                 \
            float2 u1 = *(const float2*)(q + 2);                             \
            float2 u2 = *(const float2*)(q + 4);                             \
            a = fmaf(wgt[r][0], u0.x, a);  a = fmaf(wgt[r][1], u0.y, a);     \
            a = fmaf(wgt[r][2], u1.x, a);  a = fmaf(wgt[r][3], u1.y, a);     \
            a = fmaf(wgt[r][4], u2.x, a);  a = fmaf(wgt[r][5], u2.y, a);     \
        }                                                                    \
        acc[K] = a;                                                          \
        __builtin_amdgcn_sched_barrier(0);  /* pin refill after slab reads */\
        if ((K) + 4 < C) {                                                   \
            const float* scn = smb + (size_t)((K) + 4) * HW;                 \
            GLDS16(scn + so0, ldst + ((K) & 3) * SLABB);                     \
            GLDS16(scn + so1, ldst + ((K) & 3) * SLABB + 1024);              \
        }                                                                    \
    } while (0)

    STEP( 0, 6);  STEP( 1, 6);  STEP( 2, 6);  STEP( 3, 6);  STEP( 4, 6);
    STEP( 5, 6);  STEP( 6, 6);  STEP( 7, 6);  STEP( 8, 6);  STEP( 9, 6);
    STEP(10, 6);  STEP(11, 6);  STEP(12, 6);  STEP(13, 6);  STEP(14, 6);
    STEP(15, 6);  STEP(16, 6);  STEP(17, 4);  STEP(18, 2);  STEP(19, 0);
#undef STEP

    // ---- Epilogue: coalesced scalar stores (20 classes) ----
    float* ob = out + (size_t)n * C * HW + (size_t)h * W + oc;
    #pragma unroll
    for (int c = 0; c < C; ++c)
        ob[(size_t)c * HW] = acc[c];
}

extern "C" void kernel_launch(void* const* d_in, const int* in_sizes, int n_in,
                              void* d_out, int out_size, void* d_ws, size_t ws_size,
                              hipStream_t stream) {
    const float* xyz     = (const float*)d_in[0];
    const float* softmax = (const float*)d_in[1];
    const int*   mask    = (const int*)d_in[2];
    float*       out     = (float*)d_out;

    const int grid = N * H * (W / TILE);   // 1024 blocks
    lcl_xyz_kernel<<<grid, BLK, 0, stream>>>(xyz, softmax, mask, out);
}